// Round 6
// baseline (704.543 us; speedup 1.0000x reference)
//
#include <hip/hip_runtime.h>
#include <math.h>
#include <stdint.h>

// Problem constants
#define T_TOK 8192
#define D_DIM 7168
#define E_EXP 256
#define K_SEL 8
#define G_GRP 8
#define LG_GRP 4
#define ROUTE_SCALE 2.5f

// GEMM tiling: R4's register-feasible base (BM=64, BN=128, 4 waves, wave-tile
// 32x64, 48 KB LDS, 3 blocks/CU) + counted-vmcnt raw barriers (validated for
// correctness in R5) + A-prefetch lead of 2 iterations (pa0/pa1 parity).
// R5's failure was register spill (64x64 tile @ 2 waves/SIMD), not the sync.
#define BM 64
#define BN 128
#define BK 64
#define NKT (D_DIM / BK)        // 112
#define SCALE_LO 2048.0f        // 2^11
#define INV_SCALE (1.0f / 2048.0f)

typedef _Float16 half_t;
typedef _Float16 half8 __attribute__((ext_vector_type(8)));
typedef float f32x4 __attribute__((ext_vector_type(4)));

// Wf fragment-ordered halves: [h][nb][kt][sl16][slot][8]
// offset(h,nb,kt,sl16,slot) = (((h*2+nb)*112 + kt)*16 + sl16)*512 + slot*8
#define WF_HALVES_PER_H (2 * 112 * 16 * 512)   // 1,835,008

__device__ __forceinline__ void load_lds16(const void* g, void* l) {
    __builtin_amdgcn_global_load_lds(
        (const __attribute__((address_space(1))) uint32_t*)g,
        (__attribute__((address_space(3))) uint32_t*)l, 16, 0, 0);
}

// SYNC1: retire all but the 4 newest vm ops (= A(tt+1) prefetch, which keeps
// flying); own ds_reads drained (lgkmcnt); then barrier. SYNC2: publish A
// ds_writes only. sched_barrier(0) fences both sides (rule: compiler may
// hoist reg-only MFMA past inline-asm waitcnt otherwise).
#define SYNC1() do { \
    asm volatile("s_waitcnt vmcnt(4) lgkmcnt(0)" ::: "memory"); \
    __builtin_amdgcn_sched_barrier(0); \
    __builtin_amdgcn_s_barrier(); \
    __builtin_amdgcn_sched_barrier(0); } while (0)
#define SYNC2() do { \
    asm volatile("s_waitcnt lgkmcnt(0)" ::: "memory"); \
    __builtin_amdgcn_sched_barrier(0); \
    __builtin_amdgcn_s_barrier(); \
    __builtin_amdgcn_sched_barrier(0); } while (0)

// ---------------------------------------------------------------------------
// Pre-pass: W[256][7168] fp32 -> Wf (f16 hi + scaled-lo residual), stored in
// MFMA-fragment tile order. (unchanged — layout consumed identically)
// ---------------------------------------------------------------------------
__global__ __launch_bounds__(256)
void convert_W_kernel(const float* __restrict__ W, half_t* __restrict__ Wf) {
    const int u = blockIdx.x * 256 + threadIdx.x;   // 0..229375
    const int slot = u & 63;
    const int ks   = (u >> 6) & 1;
    const int p    = (u >> 7) & 7;
    const int t2   = u >> 10;          // 0..223
    const int kt   = t2 % 112;
    const int nb   = t2 / 112;
    const int e = nb * 128 + p * 16 + (slot & 15);
    const int k = kt * 64 + ks * 32 + (slot >> 4) * 8;

    const float* src = W + (size_t)e * D_DIM + k;
    float4 v0 = *(const float4*)src;
    float4 v1 = *(const float4*)(src + 4);
    float f[8] = {v0.x, v0.y, v0.z, v0.w, v1.x, v1.y, v1.z, v1.w};
    half8 hi, lo;
    #pragma unroll
    for (int j = 0; j < 8; j++) {
        const half_t h = (half_t)f[j];
        hi[j] = h;
        lo[j] = (half_t)((f[j] - (float)h) * SCALE_LO);
    }
    *(half8*)&Wf[(size_t)u * 8] = hi;
    *(half8*)&Wf[(size_t)WF_HALVES_PER_H + (size_t)u * 8] = lo;
}

// ---------------------------------------------------------------------------
// GEMM: 3-term split-f16 MFMA, split-K=3 (uneven 38/37/37; fallback 2).
// Per iter: SYNC1 (vmcnt(4): B-hi(tt) retired, A(tt+1) flying); stage_A
// (cvt + 4 ds_write_b128); SYNC2 (lgkm only); compute:
//   [bl(tt) x8 direct | SB | B-hi(tt+1) gl_lds x4 | SB | A(tt+2) x4 | MFMAx48]
// vm queue at next SYNC1 = [B-hi x4, A x4] -> vmcnt(4) exact. A loads live
// across TWO barriers (~2 iters of lead, HBM-latency safe). bl consumption
// inside compute retires A(tt+1) before stage_A(tt+1) reads its regs.
// ---------------------------------------------------------------------------
__global__ __launch_bounds__(256, 3)
void gemm_logits_f16split(const float* __restrict__ x,
                          const half_t* __restrict__ Wf,
                          float* __restrict__ planes,
                          int nsplit) {
    __shared__ __align__(16) half_t Ah[4 * 2 * 64 * 8];   // 8 KB
    __shared__ __align__(16) half_t Al[4 * 2 * 64 * 8];   // 8 KB
    __shared__ __align__(16) half_t Bbuf[2][16][512];     // 32 KB (hi, dbuf)

    const int tid = threadIdx.x;
    const int bid = blockIdx.x;
    const int nmod  = 2 * nsplit;
    const int g     = bid % nmod;
    const int j     = bid / nmod;          // 0..127 = m_blk
    const int nb    = g & 1;
    const int split = g >> 1;              // 0..nsplit-1
    const int row0 = j * BM;

    int ks0, kt_len;
    if (nsplit == 3) { ks0 = split * 38 - (split == 2 ? 1 : 0);
                       kt_len = split ? 37 : 38; }        // 38+37+37 = 112
    else             { ks0 = split * (NKT / nsplit);
                       kt_len = NKT / nsplit; }

    const float* __restrict__ xA = x + (size_t)row0 * D_DIM;
    float* __restrict__ plane = planes + (size_t)split * T_TOK * E_EXP;

    const int wave = tid >> 6, lane = tid & 63;
    const int q = lane >> 4;
    const int mp0 = (wave >> 1) * 2;       // 2 mi-tiles of 16 rows
    const int np0 = (wave & 1) * 4;        // 4 ni-tiles of 16 cols

    // lo-plane direct-load base (R3/R4-verified): h=1 -> (2+nb)*112 block.
    const half_t* __restrict__ wfl = Wf + ((size_t)(2 + nb) * 112) * 16 * 512
                                        + (size_t)lane * 8;

    float4 pa0[2][2], pa1[2][2];           // parity-double-buffered A regs

    auto load_A = [&](float4 (&pa)[2][2], int kt) {
        const int kbase = kt * BK;
        #pragma unroll
        for (int i = 0; i < 2; i++) {
            const int u = i * 256 + tid;
            const int r = u >> 3, k8 = u & 7;
            const float* p = xA + (size_t)r * D_DIM + kbase + k8 * 8;
            pa[i][0] = *(const float4*)p;
            pa[i][1] = *(const float4*)(p + 4);
        }
    };

    auto stage_A = [&](float4 (&pa)[2][2]) {
        #pragma unroll
        for (int i = 0; i < 2; i++) {
            const int u = i * 256 + tid;
            const int r = u >> 3, k8 = u & 7;
            float f[8] = {pa[i][0].x, pa[i][0].y, pa[i][0].z, pa[i][0].w,
                          pa[i][1].x, pa[i][1].y, pa[i][1].z, pa[i][1].w};
            half8 hi, lo;
            #pragma unroll
            for (int jj = 0; jj < 8; jj++) {
                const half_t h = (half_t)f[jj];
                hi[jj] = h;
                lo[jj] = (half_t)((f[jj] - (float)h) * SCALE_LO);
            }
            const int m = r & 15, qq = k8 & 3, kss = k8 >> 2;
            const int slot = (m + 16 * qq) ^ k8;
            const int off = (((r >> 4) * 2 + kss) * 64 + slot) * 8;
            *(half8*)&Ah[off] = hi;
            *(half8*)&Al[off] = lo;
        }
    };

    // B-hi global->LDS (double-buffered): 16 slices, 4 instr/wave.
    auto issue_B = [&](int kt, int buf) {
        half_t* bb = &Bbuf[buf][0][0];
        #pragma unroll
        for (int i = 0; i < 4; i++) {
            const int sl = i * 4 + wave;            // 0..15 (hi slices only)
            const half_t* src = Wf +
                ((size_t)(nb * 112 + kt) * 16 + sl) * 512 + lane * 8;
            load_lds16(src, bb + sl * 512);
        }
    };

    f32x4 ach[2][4] = {}, acc[2][4] = {};

    auto compute = [&](int tt, int ktB, float4 (&paN)[2][2], int ktA) {
        const half_t* bb = &Bbuf[tt & 1][0][0];

        // 1) bl(tt) direct: oldest in queue, consumed at counted auto-waits
        //    (this also retires the flying A(tt+1) loads before next stage_A).
        half8 bl[4][2];
        const size_t ktoff = (size_t)(ks0 + tt) * (16 * 512);
        #pragma unroll
        for (int ni = 0; ni < 4; ni++)
            #pragma unroll
            for (int ks = 0; ks < 2; ks++) {
                const int sl = (np0 + ni) * 2 + ks;    // 0..15
                bl[ni][ks] = *(const half8*)(wfl + ktoff + (size_t)sl * 512);
            }
        __builtin_amdgcn_sched_barrier(0);
        // 2) B-hi(tt+1): drains at the NEXT SYNC1's vmcnt(4).
        issue_B(ktB, (tt + 1) & 1);
        __builtin_amdgcn_sched_barrier(0);
        // 3) A(tt+2): stays in flight across TWO barriers.
        load_A(paN, ktA);
        // 4) MFMAs (compiler schedules ds_reads + counted waits freely).
        #pragma unroll
        for (int ks = 0; ks < 2; ks++) {
            const int slot = lane ^ ((ks << 2) | q);
            half8 ah[2], al[2], bh[4];
            #pragma unroll
            for (int mi = 0; mi < 2; mi++) {
                const int off = (((mp0 + mi) * 2 + ks) * 64 + slot) * 8;
                ah[mi] = *(const half8*)&Ah[off];
                al[mi] = *(const half8*)&Al[off];
            }
            #pragma unroll
            for (int ni = 0; ni < 4; ni++) {
                const int s32 = (np0 + ni) * 2 + ks;
                bh[ni] = *(const half8*)&bb[s32 * 512 + lane * 8];
            }
            #pragma unroll
            for (int mi = 0; mi < 2; mi++)
                #pragma unroll
                for (int ni = 0; ni < 4; ni++) {
                    ach[mi][ni] = __builtin_amdgcn_mfma_f32_16x16x32_f16(ah[mi], bh[ni], ach[mi][ni], 0, 0, 0);
                    acc[mi][ni] = __builtin_amdgcn_mfma_f32_16x16x32_f16(ah[mi], bl[ni][ks], acc[mi][ni], 0, 0, 0);
                    acc[mi][ni] = __builtin_amdgcn_mfma_f32_16x16x32_f16(al[mi], bh[ni], acc[mi][ni], 0, 0, 0);
                }
        }
    };

    // Prologue queue = [A(0)x4, Bhi(0)x4, A(1)x4]; first SYNC1 vmcnt(4)
    // retires A(0)+Bhi(0), leaves A(1) flying.
    load_A(pa0, ks0);
    issue_B(ks0, 0);
    load_A(pa1, ks0 + 1);

    const int last = kt_len - 1;
    int tt = 0;
    #pragma unroll 1
    while (true) {
        // even iter (pa0); A(tt+2) -> pa0
        {
            SYNC1();
            stage_A(pa0);
            SYNC2();
            const int ktB = ks0 + (tt + 1 < kt_len ? tt + 1 : last);
            const int ktA = ks0 + (tt + 2 < kt_len ? tt + 2 : last);
            compute(tt, ktB, pa0, ktA);
        }
        if (++tt == kt_len) break;
        // odd iter (pa1); A(tt+2) -> pa1
        {
            SYNC1();
            stage_A(pa1);
            SYNC2();
            const int ktB = ks0 + (tt + 1 < kt_len ? tt + 1 : last);
            const int ktA = ks0 + (tt + 2 < kt_len ? tt + 2 : last);
            compute(tt, ktB, pa1, ktA);
        }
        if (++tt == kt_len) break;
    }

    const int col0 = nb * BN;
    #pragma unroll
    for (int mi = 0; mi < 2; mi++)
        #pragma unroll
        for (int ni = 0; ni < 4; ni++) {
            const f32x4 vh = ach[mi][ni];
            const f32x4 vc = acc[mi][ni];
            const int ex = col0 + (np0 + ni) * 16 + (lane & 15);
            #pragma unroll
            for (int r = 0; r < 4; r++) {
                const int tok = row0 + (mp0 + mi) * 16 + q * 4 + r;
                plane[(size_t)tok * E_EXP + ex] = vh[r] + vc[r] * INV_SCALE;
            }
        }
}

// ---------------------------------------------------------------------------
// Routing: one wave per token. Sums nsplit planes. No atomics.
// ---------------------------------------------------------------------------
__global__ __launch_bounds__(256)
void routing_kernel(const float* __restrict__ planes,
                    const float* __restrict__ bias,
                    float* __restrict__ out_w,
                    float* __restrict__ out_i,
                    int nsplit) {
    const int wave = threadIdx.x >> 6;
    const int lane = threadIdx.x & 63;
    const int t    = blockIdx.x * 4 + wave;

    float lg[4] = {0.f, 0.f, 0.f, 0.f};
    for (int s = 0; s < nsplit; s++) {
        const float4 l = *(const float4*)(planes + (size_t)s * T_TOK * E_EXP +
                                          (size_t)t * E_EXP + lane * 4);
        lg[0] += l.x; lg[1] += l.y; lg[2] += l.z; lg[3] += l.w;
    }
    const float4 bi = *(const float4*)(bias + lane * 4);

    float orig[4], s[4];
    #pragma unroll
    for (int j = 0; j < 4; j++)
        orig[j] = 1.0f / (1.0f + expf(-lg[j]));
    s[0] = orig[0] + bi.x; s[1] = orig[1] + bi.y;
    s[2] = orig[2] + bi.z; s[3] = orig[3] + bi.w;

    float p1 = fmaxf(s[0], s[1]), p2 = fminf(s[0], s[1]);
    float q1 = fmaxf(s[2], s[3]), q2 = fminf(s[2], s[3]);
    float m1 = fmaxf(p1, q1);
    float m2 = fmaxf(fminf(p1, q1), (p1 >= q1) ? p2 : q2);

    #pragma unroll
    for (int off = 1; off <= 4; off <<= 1) {
        float o1 = __shfl_xor(m1, off);
        float o2 = __shfl_xor(m2, off);
        float M1 = fmaxf(m1, o1);
        float M2 = fmaxf(fminf(m1, o1), (m1 >= o1) ? m2 : o2);
        m1 = M1; m2 = M2;
    }
    const float gscore = m1 + m2;

    const int g = lane >> 3;
    int cnt = 0;
    #pragma unroll
    for (int j = 0; j < G_GRP; j++) {
        float gj = __shfl(gscore, j * 8);
        cnt += (gj > gscore || (gj == gscore && j < g)) ? 1 : 0;
    }
    const bool keep = (cnt < LG_GRP);

    float smask[4];
    #pragma unroll
    for (int j = 0; j < 4; j++) smask[j] = keep ? s[j] : -INFINITY;

    float wsum = 0.0f, my_o = 0.0f;
    int my_i = 0;

    #pragma unroll
    for (int k = 0; k < K_SEL; k++) {
        float bv = smask[0]; float bo = orig[0]; int bs = 0;
        if (smask[1] > bv) { bv = smask[1]; bo = orig[1]; bs = 1; }
        if (smask[2] > bv) { bv = smask[2]; bo = orig[2]; bs = 2; }
        if (smask[3] > bv) { bv = smask[3]; bo = orig[3]; bs = 3; }
        int bidx = lane * 4 + bs;

        #pragma unroll
        for (int off = 32; off >= 1; off >>= 1) {
            float ov = __shfl_xor(bv, off);
            float oo = __shfl_xor(bo, off);
            int   oi = __shfl_xor(bidx, off);
            if (ov > bv || (ov == bv && oi < bidx)) { bv = ov; bo = oo; bidx = oi; }
        }
        wsum += bo;
        if (lane == k) { my_o = bo; my_i = bidx; }
        if ((bidx >> 2) == lane) {
            const int sl = bidx & 3;
            smask[0] = (sl == 0) ? -INFINITY : smask[0];
            smask[1] = (sl == 1) ? -INFINITY : smask[1];
            smask[2] = (sl == 2) ? -INFINITY : smask[2];
            smask[3] = (sl == 3) ? -INFINITY : smask[3];
        }
    }

    if (lane < K_SEL) {
        out_w[(size_t)t * K_SEL + lane] = my_o * ROUTE_SCALE / wsum;
        out_i[(size_t)t * K_SEL + lane] = (float)my_i;
    }
}

// ---------------------------------------------------------------------------
// Counts: block e scans all T*K indices for expert e. L2-hot, zero atomics.
// ---------------------------------------------------------------------------
__global__ __launch_bounds__(256)
void count_kernel(const float* __restrict__ idxf, float* __restrict__ out_c) {
    const float fe = (float)blockIdx.x;
    int c = 0;
    const float4* p = (const float4*)idxf;          // T*K/4 = 16384
    for (int i = threadIdx.x; i < (T_TOK * K_SEL / 4); i += 256) {
        float4 v = p[i];
        c += (v.x == fe) + (v.y == fe) + (v.z == fe) + (v.w == fe);
    }
    __shared__ int red[4];
    #pragma unroll
    for (int off = 32; off >= 1; off >>= 1) c += __shfl_down(c, off);
    if ((threadIdx.x & 63) == 0) red[threadIdx.x >> 6] = c;
    __syncthreads();
    if (threadIdx.x == 0)
        out_c[blockIdx.x] = (float)(red[0] + red[1] + red[2] + red[3]);
}

// ---------------- launch ----------------
extern "C" void kernel_launch(void* const* d_in, const int* in_sizes, int n_in,
                              void* d_out, int out_size, void* d_ws, size_t ws_size,
                              hipStream_t stream) {
    const float* x    = (const float*)d_in[0];
    const float* W    = (const float*)d_in[1];
    const float* bias = (const float*)d_in[2];

    float* out   = (float*)d_out;
    float* out_w = out;
    float* out_i = out + (size_t)T_TOK * K_SEL;
    float* out_c = out + (size_t)2 * T_TOK * K_SEL;

    const size_t planeN  = (size_t)T_TOK * E_EXP;              // floats per plane
    const size_t wfBytes = (size_t)2 * WF_HALVES_PER_H * sizeof(half_t);

    // split-K=3 (grid 768 = 3 blocks/CU at 48 KB LDS); fallback split-K=2.
    int nsplit = 3;
    if (ws_size != 0 && ws_size < 3 * planeN * sizeof(float) + wfBytes)
        nsplit = 2;
    const int grid = 128 * 2 * nsplit;

    float* planes = (float*)d_ws;
    half_t* Wf    = (half_t*)(planes + (size_t)nsplit * planeN);

    hipLaunchKernelGGL(convert_W_kernel, dim3(896), dim3(256), 0, stream, W, Wf);
    hipLaunchKernelGGL(gemm_logits_f16split, dim3(grid), dim3(256), 0, stream,
                       x, Wf, planes, nsplit);
    hipLaunchKernelGGL(routing_kernel, dim3(T_TOK / 4), dim3(256), 0, stream,
                       planes, bias, out_w, out_i, nsplit);
    hipLaunchKernelGGL(count_kernel, dim3(E_EXP), dim3(256), 0, stream,
                       out_i, out_c);
}

// Round 8
// 409.599 us; speedup vs baseline: 1.7201x; 1.7201x over previous
//
#include <hip/hip_runtime.h>
#include <math.h>
#include <stdint.h>

// Problem constants
#define T_TOK 8192
#define D_DIM 7168
#define E_EXP 256
#define K_SEL 8
#define G_GRP 8
#define LG_GRP 4
#define ROUTE_SCALE 2.5f

// GEMM tiling (R0 structure — session best, 141 us):
// 64 tok x 128 exp block, 4 waves, wave-tile 32x64, split-K=2, grid 512 =
// 2 blocks/CU. B hi+lo double-buffered in LDS via global_load_lds; prefetch
// issued at compute start, drained by the next barrier (one compute of
// latency cover); two independent blocks/CU hide each other's barriers.
// R7 deltas vs R0 (both register-safe, ~124 VGPR < 256 cap at (256,2)):
//  1) convert hoisted out of the barrier window (R1-validated split):
//     only 8 ds_write_b128 remain between the two barriers.
//  2) load_A issued BEFORE issue_B: A is oldest in the vm queue, so
//     convert_A's compiler wait is counted (B stays in flight), and the
//     barrier's vmcnt(0) sees B issued a full compute earlier.
#define BM 64
#define BN 128
#define BK 64
#define NKT (D_DIM / BK)        // 112
#define KT_HALF (NKT / 2)       // 56 (split-K=2)
#define SCALE_LO 2048.0f        // 2^11
#define INV_SCALE (1.0f / 2048.0f)

typedef _Float16 half_t;
typedef _Float16 half8 __attribute__((ext_vector_type(8)));
typedef float f32x4 __attribute__((ext_vector_type(4)));

// Wf fragment-ordered halves: [h][nb][kt][sl16][slot][8]
// offset(h,nb,kt,sl16,slot) = (((h*2+nb)*112 + kt)*16 + sl16)*512 + slot*8
#define WF_HALVES_PER_H (2 * 112 * 16 * 512)   // 1,835,008

__device__ __forceinline__ void load_lds16(const void* g, void* l) {
    __builtin_amdgcn_global_load_lds(
        (const __attribute__((address_space(1))) uint32_t*)g,
        (__attribute__((address_space(3))) uint32_t*)l, 16, 0, 0);
}

// ---------------------------------------------------------------------------
// Pre-pass: W[256][7168] fp32 -> Wf (f16 hi + scaled-lo residual), stored in
// MFMA-fragment tile order so GEMM B-staging is a pure global_load_lds copy.
// ---------------------------------------------------------------------------
__global__ __launch_bounds__(256)
void convert_W_kernel(const float* __restrict__ W, half_t* __restrict__ Wf) {
    const int u = blockIdx.x * 256 + threadIdx.x;   // 0..229375
    const int slot = u & 63;
    const int ks   = (u >> 6) & 1;
    const int p    = (u >> 7) & 7;
    const int t2   = u >> 10;          // 0..223
    const int kt   = t2 % 112;
    const int nb   = t2 / 112;
    const int e = nb * 128 + p * 16 + (slot & 15);
    const int k = kt * 64 + ks * 32 + (slot >> 4) * 8;

    const float* src = W + (size_t)e * D_DIM + k;
    float4 v0 = *(const float4*)src;
    float4 v1 = *(const float4*)(src + 4);
    float f[8] = {v0.x, v0.y, v0.z, v0.w, v1.x, v1.y, v1.z, v1.w};
    half8 hi, lo;
    #pragma unroll
    for (int j = 0; j < 8; j++) {
        const half_t h = (half_t)f[j];
        hi[j] = h;
        lo[j] = (half_t)((f[j] - (float)h) * SCALE_LO);
    }
    *(half8*)&Wf[(size_t)u * 8] = hi;
    *(half8*)&Wf[(size_t)WF_HALVES_PER_H + (size_t)u * 8] = lo;
}

// ---------------------------------------------------------------------------
// GEMM: partial logits via 3-term split-f16 MFMA, split-K=2.
// Block: 64 tok x 128 exp x half-K, 256 thr (4 waves, wave-tile 32x64).
// Grid 512 = 2 blocks/CU. A: fp32->regs->cvt(pre-barrier)->ds_write (XOR
// swizzle, round-0 verified). B: global_load_lds from pre-converted Wf,
// double-buffered, prefetched during compute so the barrier vmcnt drain
// lands a full compute after issue.
// ---------------------------------------------------------------------------
__global__ __launch_bounds__(256, 2)
void gemm_logits_f16split(const float* __restrict__ x,
                          const half_t* __restrict__ Wf,
                          float* __restrict__ plane0,
                          float* __restrict__ plane1) {
    __shared__ __align__(16) half_t Ah[4 * 2 * 64 * 8];   // 8 KB
    __shared__ __align__(16) half_t Al[4 * 2 * 64 * 8];   // 8 KB
    __shared__ __align__(16) half_t Bbuf[2][32][512];     // 64 KB (hi|lo x 16)

    const int tid = threadIdx.x;
    const int bid = blockIdx.x;
    // nb fastest: the 4 blocks covering one m-row (2 nb x 2 split) are
    // temporally adjacent -> x rows stream from HBM ~once.
    const int nb    = bid & 1;
    const int split = (bid >> 1) & 1;
    const int m_blk = bid >> 2;
    const int row0 = m_blk * BM;
    const int ks0  = split * KT_HALF;

    const float* __restrict__ xA = x + (size_t)row0 * D_DIM;
    float* __restrict__ plane = split ? plane1 : plane0;

    const int wave = tid >> 6, lane = tid & 63;
    const int q = lane >> 4;
    const int mp0 = (wave >> 1) * 2;
    const int np0 = (wave & 1) * 4;

    float4 pa[2][2];
    half8 hreg[2], lreg[2];

    auto load_A = [&](int kt) {
        const int kbase = kt * BK;
        #pragma unroll
        for (int i = 0; i < 2; i++) {
            const int u = i * 256 + tid;
            const int r = u >> 3, k8 = u & 7;
            const float* p = xA + (size_t)r * D_DIM + kbase + k8 * 8;
            pa[i][0] = *(const float4*)p;
            pa[i][1] = *(const float4*)(p + 4);
        }
    };

    // fp32 -> (hi, scaled-lo) into registers. Pure VALU, no LDS: runs BEFORE
    // the first barrier, so only the ds_writes sit inside the window.
    auto convert_A = [&]() {
        #pragma unroll
        for (int i = 0; i < 2; i++) {
            float f[8] = {pa[i][0].x, pa[i][0].y, pa[i][0].z, pa[i][0].w,
                          pa[i][1].x, pa[i][1].y, pa[i][1].z, pa[i][1].w};
            half8 hi, lo;
            #pragma unroll
            for (int jj = 0; jj < 8; jj++) {
                const half_t h = (half_t)f[jj];
                hi[jj] = h;
                lo[jj] = (half_t)((f[jj] - (float)h) * SCALE_LO);
            }
            hreg[i] = hi;
            lreg[i] = lo;
        }
    };

    // Only the 4 ds_write_b128 pairs sit between the two barriers.
    auto write_A = [&]() {
        #pragma unroll
        for (int i = 0; i < 2; i++) {
            const int u = i * 256 + tid;
            const int r = u >> 3, k8 = u & 7;
            const int m = r & 15, qq = k8 & 3, kss = k8 >> 2;
            const int slot = (m + 16 * qq) ^ k8;
            const int off = (((r >> 4) * 2 + kss) * 64 + slot) * 8;
            *(half8*)&Ah[off] = hreg[i];
            *(half8*)&Al[off] = lreg[i];
        }
    };

    auto issue_B = [&](int tt) {
        const int kt = ks0 + tt;
        half_t* bb = &Bbuf[tt & 1][0][0];
        #pragma unroll
        for (int i = 0; i < 8; i++) {
            const int s32 = i * 4 + wave;           // 0..31
            const int h = s32 >> 4, sl = s32 & 15;
            const half_t* src = Wf +
                ((size_t)((h * 2 + nb) * 112 + kt) * 16 + sl) * 512 + lane * 8;
            load_lds16(src, bb + s32 * 512);
        }
    };

    f32x4 ach[2][4] = {}, acc[2][4] = {};

    auto compute = [&](int tt) {
        const half_t* bb = &Bbuf[tt & 1][0][0];
        #pragma unroll
        for (int ks = 0; ks < 2; ks++) {
            const int slot = lane ^ ((ks << 2) | q);
            half8 ah[2], al[2], bh[4], bl[4];
            #pragma unroll
            for (int mi = 0; mi < 2; mi++) {
                const int off = (((mp0 + mi) * 2 + ks) * 64 + slot) * 8;
                ah[mi] = *(const half8*)&Ah[off];
                al[mi] = *(const half8*)&Al[off];
            }
            #pragma unroll
            for (int ni = 0; ni < 4; ni++) {
                const int s32 = (np0 + ni) * 2 + ks;
                bh[ni] = *(const half8*)&bb[s32 * 512 + lane * 8];
                bl[ni] = *(const half8*)&bb[(16 + s32) * 512 + lane * 8];
            }
            #pragma unroll
            for (int mi = 0; mi < 2; mi++)
                #pragma unroll
                for (int ni = 0; ni < 4; ni++) {
                    ach[mi][ni] = __builtin_amdgcn_mfma_f32_16x16x32_f16(ah[mi], bh[ni], ach[mi][ni], 0, 0, 0);
                    acc[mi][ni] = __builtin_amdgcn_mfma_f32_16x16x32_f16(ah[mi], bl[ni], acc[mi][ni], 0, 0, 0);
                    acc[mi][ni] = __builtin_amdgcn_mfma_f32_16x16x32_f16(al[mi], bh[ni], acc[mi][ni], 0, 0, 0);
                }
        }
    };

    issue_B(0);
    load_A(ks0);

    #pragma unroll 1
    for (int tt = 0; tt < KT_HALF; tt++) {
        convert_A();                     // waits (counted) on A(tt) only
        __syncthreads();                 // drains B-lds(tt)
        write_A();                       // 4x2 ds_write_b128 only
        __syncthreads();                 // A ds_writes visible
        if (tt + 1 < KT_HALF) {
            load_A(ks0 + tt + 1);        // A first: oldest in vm queue
            issue_B(tt + 1);             // B lands during compute
        }
        compute(tt);
    }

    const int col0 = nb * BN;
    #pragma unroll
    for (int mi = 0; mi < 2; mi++)
        #pragma unroll
        for (int ni = 0; ni < 4; ni++) {
            const f32x4 vh = ach[mi][ni];
            const f32x4 vc = acc[mi][ni];
            const int ex = col0 + (np0 + ni) * 16 + (lane & 15);
            #pragma unroll
            for (int r = 0; r < 4; r++) {
                const int tok = row0 + (mp0 + mi) * 16 + q * 4 + r;
                plane[(size_t)tok * E_EXP + ex] = vh[r] + vc[r] * INV_SCALE;
            }
        }
}

// ---------------------------------------------------------------------------
// Routing: one wave per token. Reads both split-K planes. No atomics.
// ---------------------------------------------------------------------------
__global__ __launch_bounds__(256)
void routing_kernel(const float* __restrict__ plane0,
                    const float* __restrict__ plane1,
                    const float* __restrict__ bias,
                    float* __restrict__ out_w,
                    float* __restrict__ out_i) {
    const int wave = threadIdx.x >> 6;
    const int lane = threadIdx.x & 63;
    const int t    = blockIdx.x * 4 + wave;

    const float4 l0 = *(const float4*)(plane0 + (size_t)t * E_EXP + lane * 4);
    const float4 l1 = *(const float4*)(plane1 + (size_t)t * E_EXP + lane * 4);
    const float4 bi = *(const float4*)(bias + lane * 4);
    float lg[4] = {l0.x + l1.x, l0.y + l1.y, l0.z + l1.z, l0.w + l1.w};

    float orig[4], s[4];
    #pragma unroll
    for (int j = 0; j < 4; j++)
        orig[j] = 1.0f / (1.0f + expf(-lg[j]));
    s[0] = orig[0] + bi.x; s[1] = orig[1] + bi.y;
    s[2] = orig[2] + bi.z; s[3] = orig[3] + bi.w;

    float p1 = fmaxf(s[0], s[1]), p2 = fminf(s[0], s[1]);
    float q1 = fmaxf(s[2], s[3]), q2 = fminf(s[2], s[3]);
    float m1 = fmaxf(p1, q1);
    float m2 = fmaxf(fminf(p1, q1), (p1 >= q1) ? p2 : q2);

    #pragma unroll
    for (int off = 1; off <= 4; off <<= 1) {
        float o1 = __shfl_xor(m1, off);
        float o2 = __shfl_xor(m2, off);
        float M1 = fmaxf(m1, o1);
        float M2 = fmaxf(fminf(m1, o1), (m1 >= o1) ? m2 : o2);
        m1 = M1; m2 = M2;
    }
    const float gscore = m1 + m2;

    const int g = lane >> 3;
    int cnt = 0;
    #pragma unroll
    for (int j = 0; j < G_GRP; j++) {
        float gj = __shfl(gscore, j * 8);
        cnt += (gj > gscore || (gj == gscore && j < g)) ? 1 : 0;
    }
    const bool keep = (cnt < LG_GRP);

    float smask[4];
    #pragma unroll
    for (int j = 0; j < 4; j++) smask[j] = keep ? s[j] : -INFINITY;

    float wsum = 0.0f, my_o = 0.0f;
    int my_i = 0;

    #pragma unroll
    for (int k = 0; k < K_SEL; k++) {
        float bv = smask[0]; float bo = orig[0]; int bs = 0;
        if (smask[1] > bv) { bv = smask[1]; bo = orig[1]; bs = 1; }
        if (smask[2] > bv) { bv = smask[2]; bo = orig[2]; bs = 2; }
        if (smask[3] > bv) { bv = smask[3]; bo = orig[3]; bs = 3; }
        int bidx = lane * 4 + bs;

        #pragma unroll
        for (int off = 32; off >= 1; off >>= 1) {
            float ov = __shfl_xor(bv, off);
            float oo = __shfl_xor(bo, off);
            int   oi = __shfl_xor(bidx, off);
            if (ov > bv || (ov == bv && oi < bidx)) { bv = ov; bo = oo; bidx = oi; }
        }
        wsum += bo;
        if (lane == k) { my_o = bo; my_i = bidx; }
        if ((bidx >> 2) == lane) {
            const int sl = bidx & 3;
            smask[0] = (sl == 0) ? -INFINITY : smask[0];
            smask[1] = (sl == 1) ? -INFINITY : smask[1];
            smask[2] = (sl == 2) ? -INFINITY : smask[2];
            smask[3] = (sl == 3) ? -INFINITY : smask[3];
        }
    }

    if (lane < K_SEL) {
        out_w[(size_t)t * K_SEL + lane] = my_o * ROUTE_SCALE / wsum;
        out_i[(size_t)t * K_SEL + lane] = (float)my_i;
    }
}

// ---------------------------------------------------------------------------
// Counts: block e scans all T*K indices for expert e. L2-hot, zero atomics.
// ---------------------------------------------------------------------------
__global__ __launch_bounds__(256)
void count_kernel(const float* __restrict__ idxf, float* __restrict__ out_c) {
    const float fe = (float)blockIdx.x;
    int c = 0;
    const float4* p = (const float4*)idxf;          // T*K/4 = 16384
    for (int i = threadIdx.x; i < (T_TOK * K_SEL / 4); i += 256) {
        float4 v = p[i];
        c += (v.x == fe) + (v.y == fe) + (v.z == fe) + (v.w == fe);
    }
    __shared__ int red[4];
    #pragma unroll
    for (int off = 32; off >= 1; off >>= 1) c += __shfl_down(c, off);
    if ((threadIdx.x & 63) == 0) red[threadIdx.x >> 6] = c;
    __syncthreads();
    if (threadIdx.x == 0)
        out_c[blockIdx.x] = (float)(red[0] + red[1] + red[2] + red[3]);
}

// ---------------- launch ----------------
extern "C" void kernel_launch(void* const* d_in, const int* in_sizes, int n_in,
                              void* d_out, int out_size, void* d_ws, size_t ws_size,
                              hipStream_t stream) {
    const float* x    = (const float*)d_in[0];
    const float* W    = (const float*)d_in[1];
    const float* bias = (const float*)d_in[2];

    float* out   = (float*)d_out;
    float* out_w = out;
    float* out_i = out + (size_t)T_TOK * K_SEL;
    float* out_c = out + (size_t)2 * T_TOK * K_SEL;

    float* plane0 = (float*)d_ws;                          // 8 MB
    float* plane1 = plane0 + (size_t)T_TOK * E_EXP;        // 8 MB
    half_t* Wf    = (half_t*)(plane1 + (size_t)T_TOK * E_EXP);  // 7.34 MB

    hipLaunchKernelGGL(convert_W_kernel, dim3(896), dim3(256), 0, stream, W, Wf);
    hipLaunchKernelGGL(gemm_logits_f16split, dim3(512), dim3(256), 0, stream,
                       x, Wf, plane0, plane1);
    hipLaunchKernelGGL(routing_kernel, dim3(T_TOK / 4), dim3(256), 0, stream,
                       plane0, plane1, bias, out_w, out_i);
    hipLaunchKernelGGL(count_kernel, dim3(E_EXP), dim3(256), 0, stream,
                       out_i, out_c);
}

// Round 9
// 396.006 us; speedup vs baseline: 1.7791x; 1.0343x over previous
//
#include <hip/hip_runtime.h>
#include <math.h>
#include <stdint.h>

// Problem constants
#define T_TOK 8192
#define D_DIM 7168
#define E_EXP 256
#define K_SEL 8
#define G_GRP 8
#define LG_GRP 4
#define ROUTE_SCALE 2.5f

// GEMM tiling (R0 structure — session best, 141 us GEMM / 393.6 us total):
// 64 tok x 128 exp block, 4 waves, wave-tile 32x64, split-K=2, grid 512 =
// 2 independent blocks/CU. B hi+lo double-buffered in LDS via
// global_load_lds, prefetched at compute start so the next barrier's
// vmcnt(0) drain lands a full compute after issue; the co-resident block
// hides each barrier. A: fp32->regs->cvt->ds_write between barriers
// (XOR swizzle, round-0 verified).
// R9 delta vs R0 (only change): s_setprio(1) around the MFMA nest (T5).
// The 2 blocks/CU are unsynchronized -> waves sit at different phases on
// each SIMD; setprio lets a wave in its MFMA cluster win issue arbitration
// over the other block's staging waves. Register/LDS/structure neutral.
#define BM 64
#define BN 128
#define BK 64
#define NKT (D_DIM / BK)        // 112
#define KT_HALF (NKT / 2)       // 56 (split-K=2)
#define SCALE_LO 2048.0f        // 2^11
#define INV_SCALE (1.0f / 2048.0f)

typedef _Float16 half_t;
typedef _Float16 half8 __attribute__((ext_vector_type(8)));
typedef float f32x4 __attribute__((ext_vector_type(4)));

// Wf fragment-ordered halves: [h][nb][kt][sl16][slot][8]
// offset(h,nb,kt,sl16,slot) = (((h*2+nb)*112 + kt)*16 + sl16)*512 + slot*8
#define WF_HALVES_PER_H (2 * 112 * 16 * 512)   // 1,835,008

__device__ __forceinline__ void load_lds16(const void* g, void* l) {
    __builtin_amdgcn_global_load_lds(
        (const __attribute__((address_space(1))) uint32_t*)g,
        (__attribute__((address_space(3))) uint32_t*)l, 16, 0, 0);
}

// ---------------------------------------------------------------------------
// Pre-pass: W[256][7168] fp32 -> Wf (f16 hi + scaled-lo residual), stored in
// MFMA-fragment tile order so GEMM B-staging is a pure global_load_lds copy.
// ---------------------------------------------------------------------------
__global__ __launch_bounds__(256)
void convert_W_kernel(const float* __restrict__ W, half_t* __restrict__ Wf) {
    const int u = blockIdx.x * 256 + threadIdx.x;   // 0..229375
    const int slot = u & 63;
    const int ks   = (u >> 6) & 1;
    const int p    = (u >> 7) & 7;
    const int t2   = u >> 10;          // 0..223
    const int kt   = t2 % 112;
    const int nb   = t2 / 112;
    const int e = nb * 128 + p * 16 + (slot & 15);
    const int k = kt * 64 + ks * 32 + (slot >> 4) * 8;

    const float* src = W + (size_t)e * D_DIM + k;
    float4 v0 = *(const float4*)src;
    float4 v1 = *(const float4*)(src + 4);
    float f[8] = {v0.x, v0.y, v0.z, v0.w, v1.x, v1.y, v1.z, v1.w};
    half8 hi, lo;
    #pragma unroll
    for (int j = 0; j < 8; j++) {
        const half_t h = (half_t)f[j];
        hi[j] = h;
        lo[j] = (half_t)((f[j] - (float)h) * SCALE_LO);
    }
    *(half8*)&Wf[(size_t)u * 8] = hi;
    *(half8*)&Wf[(size_t)WF_HALVES_PER_H + (size_t)u * 8] = lo;
}

// ---------------------------------------------------------------------------
// GEMM: partial logits via 3-term split-f16 MFMA, split-K=2.
// Block: 64 tok x 128 exp x half-K, 256 thr (4 waves, wave-tile 32x64).
// Grid 512 = 2 blocks/CU. A: fp32->regs->cvt->ds_write (XOR swizzle,
// round-0 verified). B: global_load_lds from pre-converted Wf,
// double-buffered, prefetched during compute so the barrier vmcnt drain
// lands post-compute.
// ---------------------------------------------------------------------------
__global__ __launch_bounds__(256, 2)
void gemm_logits_f16split(const float* __restrict__ x,
                          const half_t* __restrict__ Wf,
                          float* __restrict__ plane0,
                          float* __restrict__ plane1) {
    __shared__ __align__(16) half_t Ah[4 * 2 * 64 * 8];   // 8 KB
    __shared__ __align__(16) half_t Al[4 * 2 * 64 * 8];   // 8 KB
    __shared__ __align__(16) half_t Bbuf[2][32][512];     // 64 KB (hi|lo x 16)

    const int tid = threadIdx.x;
    const int bid = blockIdx.x;
    // nb fastest: the 4 blocks covering one m-row (2 nb x 2 split) are
    // temporally adjacent -> x rows stream from HBM ~once.
    const int nb    = bid & 1;
    const int split = (bid >> 1) & 1;
    const int m_blk = bid >> 2;
    const int row0 = m_blk * BM;
    const int ks0  = split * KT_HALF;

    const float* __restrict__ xA = x + (size_t)row0 * D_DIM;
    float* __restrict__ plane = split ? plane1 : plane0;

    const int wave = tid >> 6, lane = tid & 63;
    const int q = lane >> 4;
    const int mp0 = (wave >> 1) * 2;
    const int np0 = (wave & 1) * 4;

    float4 pa[2][2];

    auto load_A = [&](int kt) {
        const int kbase = kt * BK;
        #pragma unroll
        for (int i = 0; i < 2; i++) {
            const int u = i * 256 + tid;
            const int r = u >> 3, k8 = u & 7;
            const float* p = xA + (size_t)r * D_DIM + kbase + k8 * 8;
            pa[i][0] = *(const float4*)p;
            pa[i][1] = *(const float4*)(p + 4);
        }
    };

    auto stage_A = [&]() {
        #pragma unroll
        for (int i = 0; i < 2; i++) {
            const int u = i * 256 + tid;
            const int r = u >> 3, k8 = u & 7;
            float f[8] = {pa[i][0].x, pa[i][0].y, pa[i][0].z, pa[i][0].w,
                          pa[i][1].x, pa[i][1].y, pa[i][1].z, pa[i][1].w};
            half8 hi, lo;
            #pragma unroll
            for (int j = 0; j < 8; j++) {
                const half_t h = (half_t)f[j];
                hi[j] = h;
                lo[j] = (half_t)((f[j] - (float)h) * SCALE_LO);
            }
            const int m = r & 15, qq = k8 & 3, kss = k8 >> 2;
            const int slot = (m + 16 * qq) ^ k8;
            const int off = (((r >> 4) * 2 + kss) * 64 + slot) * 8;
            *(half8*)&Ah[off] = hi;
            *(half8*)&Al[off] = lo;
        }
    };

    auto issue_B = [&](int tt) {
        const int kt = ks0 + tt;
        half_t* bb = &Bbuf[tt & 1][0][0];
        #pragma unroll
        for (int i = 0; i < 8; i++) {
            const int s32 = i * 4 + wave;           // 0..31
            const int h = s32 >> 4, sl = s32 & 15;
            const half_t* src = Wf +
                ((size_t)((h * 2 + nb) * 112 + kt) * 16 + sl) * 512 + lane * 8;
            load_lds16(src, bb + s32 * 512);
        }
    };

    f32x4 ach[2][4] = {}, acc[2][4] = {};

    auto compute = [&](int tt) {
        const half_t* bb = &Bbuf[tt & 1][0][0];
        #pragma unroll
        for (int ks = 0; ks < 2; ks++) {
            const int slot = lane ^ ((ks << 2) | q);
            half8 ah[2], al[2], bh[4], bl[4];
            #pragma unroll
            for (int mi = 0; mi < 2; mi++) {
                const int off = (((mp0 + mi) * 2 + ks) * 64 + slot) * 8;
                ah[mi] = *(const half8*)&Ah[off];
                al[mi] = *(const half8*)&Al[off];
            }
            #pragma unroll
            for (int ni = 0; ni < 4; ni++) {
                const int s32 = (np0 + ni) * 2 + ks;
                bh[ni] = *(const half8*)&bb[s32 * 512 + lane * 8];
                bl[ni] = *(const half8*)&bb[(16 + s32) * 512 + lane * 8];
            }
            // T5: prefer this wave while it feeds the matrix pipe; the
            // co-resident block's staging waves yield issue slots.
            __builtin_amdgcn_s_setprio(1);
            #pragma unroll
            for (int mi = 0; mi < 2; mi++)
                #pragma unroll
                for (int ni = 0; ni < 4; ni++) {
                    ach[mi][ni] = __builtin_amdgcn_mfma_f32_16x16x32_f16(ah[mi], bh[ni], ach[mi][ni], 0, 0, 0);
                    acc[mi][ni] = __builtin_amdgcn_mfma_f32_16x16x32_f16(ah[mi], bl[ni], acc[mi][ni], 0, 0, 0);
                    acc[mi][ni] = __builtin_amdgcn_mfma_f32_16x16x32_f16(al[mi], bh[ni], acc[mi][ni], 0, 0, 0);
                }
            __builtin_amdgcn_s_setprio(0);
        }
    };

    issue_B(0);
    load_A(ks0);

    #pragma unroll 1
    for (int tt = 0; tt < KT_HALF; tt++) {
        __syncthreads();                 // drains B-lds(tt) + A-regs(tt)
        stage_A();
        __syncthreads();                 // A ds_writes visible; nothing global in flight
        if (tt + 1 < KT_HALF) {
            issue_B(tt + 1);             // lands during compute, drains next barrier
            load_A(ks0 + tt + 1);
        }
        compute(tt);
    }

    const int col0 = nb * BN;
    #pragma unroll
    for (int mi = 0; mi < 2; mi++)
        #pragma unroll
        for (int ni = 0; ni < 4; ni++) {
            const f32x4 vh = ach[mi][ni];
            const f32x4 vc = acc[mi][ni];
            const int ex = col0 + (np0 + ni) * 16 + (lane & 15);
            #pragma unroll
            for (int r = 0; r < 4; r++) {
                const int tok = row0 + (mp0 + mi) * 16 + q * 4 + r;
                plane[(size_t)tok * E_EXP + ex] = vh[r] + vc[r] * INV_SCALE;
            }
        }
}

// ---------------------------------------------------------------------------
// Routing: one wave per token. Reads both split-K planes. No atomics.
// ---------------------------------------------------------------------------
__global__ __launch_bounds__(256)
void routing_kernel(const float* __restrict__ plane0,
                    const float* __restrict__ plane1,
                    const float* __restrict__ bias,
                    float* __restrict__ out_w,
                    float* __restrict__ out_i) {
    const int wave = threadIdx.x >> 6;
    const int lane = threadIdx.x & 63;
    const int t    = blockIdx.x * 4 + wave;

    const float4 l0 = *(const float4*)(plane0 + (size_t)t * E_EXP + lane * 4);
    const float4 l1 = *(const float4*)(plane1 + (size_t)t * E_EXP + lane * 4);
    const float4 bi = *(const float4*)(bias + lane * 4);
    float lg[4] = {l0.x + l1.x, l0.y + l1.y, l0.z + l1.z, l0.w + l1.w};

    float orig[4], s[4];
    #pragma unroll
    for (int j = 0; j < 4; j++)
        orig[j] = 1.0f / (1.0f + expf(-lg[j]));
    s[0] = orig[0] + bi.x; s[1] = orig[1] + bi.y;
    s[2] = orig[2] + bi.z; s[3] = orig[3] + bi.w;

    float p1 = fmaxf(s[0], s[1]), p2 = fminf(s[0], s[1]);
    float q1 = fmaxf(s[2], s[3]), q2 = fminf(s[2], s[3]);
    float m1 = fmaxf(p1, q1);
    float m2 = fmaxf(fminf(p1, q1), (p1 >= q1) ? p2 : q2);

    #pragma unroll
    for (int off = 1; off <= 4; off <<= 1) {
        float o1 = __shfl_xor(m1, off);
        float o2 = __shfl_xor(m2, off);
        float M1 = fmaxf(m1, o1);
        float M2 = fmaxf(fminf(m1, o1), (m1 >= o1) ? m2 : o2);
        m1 = M1; m2 = M2;
    }
    const float gscore = m1 + m2;

    const int g = lane >> 3;
    int cnt = 0;
    #pragma unroll
    for (int j = 0; j < G_GRP; j++) {
        float gj = __shfl(gscore, j * 8);
        cnt += (gj > gscore || (gj == gscore && j < g)) ? 1 : 0;
    }
    const bool keep = (cnt < LG_GRP);

    float smask[4];
    #pragma unroll
    for (int j = 0; j < 4; j++) smask[j] = keep ? s[j] : -INFINITY;

    float wsum = 0.0f, my_o = 0.0f;
    int my_i = 0;

    #pragma unroll
    for (int k = 0; k < K_SEL; k++) {
        float bv = smask[0]; float bo = orig[0]; int bs = 0;
        if (smask[1] > bv) { bv = smask[1]; bo = orig[1]; bs = 1; }
        if (smask[2] > bv) { bv = smask[2]; bo = orig[2]; bs = 2; }
        if (smask[3] > bv) { bv = smask[3]; bo = orig[3]; bs = 3; }
        int bidx = lane * 4 + bs;

        #pragma unroll
        for (int off = 32; off >= 1; off >>= 1) {
            float ov = __shfl_xor(bv, off);
            float oo = __shfl_xor(bo, off);
            int   oi = __shfl_xor(bidx, off);
            if (ov > bv || (ov == bv && oi < bidx)) { bv = ov; bo = oo; bidx = oi; }
        }
        wsum += bo;
        if (lane == k) { my_o = bo; my_i = bidx; }
        if ((bidx >> 2) == lane) {
            const int sl = bidx & 3;
            smask[0] = (sl == 0) ? -INFINITY : smask[0];
            smask[1] = (sl == 1) ? -INFINITY : smask[1];
            smask[2] = (sl == 2) ? -INFINITY : smask[2];
            smask[3] = (sl == 3) ? -INFINITY : smask[3];
        }
    }

    if (lane < K_SEL) {
        out_w[(size_t)t * K_SEL + lane] = my_o * ROUTE_SCALE / wsum;
        out_i[(size_t)t * K_SEL + lane] = (float)my_i;
    }
}

// ---------------------------------------------------------------------------
// Counts: block e scans all T*K indices for expert e. L2-hot, zero atomics.
// ---------------------------------------------------------------------------
__global__ __launch_bounds__(256)
void count_kernel(const float* __restrict__ idxf, float* __restrict__ out_c) {
    const float fe = (float)blockIdx.x;
    int c = 0;
    const float4* p = (const float4*)idxf;          // T*K/4 = 16384
    for (int i = threadIdx.x; i < (T_TOK * K_SEL / 4); i += 256) {
        float4 v = p[i];
        c += (v.x == fe) + (v.y == fe) + (v.z == fe) + (v.w == fe);
    }
    __shared__ int red[4];
    #pragma unroll
    for (int off = 32; off >= 1; off >>= 1) c += __shfl_down(c, off);
    if ((threadIdx.x & 63) == 0) red[threadIdx.x >> 6] = c;
    __syncthreads();
    if (threadIdx.x == 0)
        out_c[blockIdx.x] = (float)(red[0] + red[1] + red[2] + red[3]);
}

// ---------------- launch ----------------
extern "C" void kernel_launch(void* const* d_in, const int* in_sizes, int n_in,
                              void* d_out, int out_size, void* d_ws, size_t ws_size,
                              hipStream_t stream) {
    const float* x    = (const float*)d_in[0];
    const float* W    = (const float*)d_in[1];
    const float* bias = (const float*)d_in[2];

    float* out   = (float*)d_out;
    float* out_w = out;
    float* out_i = out + (size_t)T_TOK * K_SEL;
    float* out_c = out + (size_t)2 * T_TOK * K_SEL;

    float* plane0 = (float*)d_ws;                          // 8 MB
    float* plane1 = plane0 + (size_t)T_TOK * E_EXP;        // 8 MB
    half_t* Wf    = (half_t*)(plane1 + (size_t)T_TOK * E_EXP);  // 7.34 MB

    hipLaunchKernelGGL(convert_W_kernel, dim3(896), dim3(256), 0, stream, W, Wf);
    hipLaunchKernelGGL(gemm_logits_f16split, dim3(512), dim3(256), 0, stream,
                       x, Wf, plane0, plane1);
    hipLaunchKernelGGL(routing_kernel, dim3(T_TOK / 4), dim3(256), 0, stream,
                       plane0, plane1, bias, out_w, out_i);
    hipLaunchKernelGGL(count_kernel, dim3(E_EXP), dim3(256), 0, stream,
                       out_i, out_c);
}